// Round 9
// baseline (125.750 us; speedup 1.0000x reference)
//
#include <hip/hip_runtime.h>
#include <hip/hip_bf16.h>

typedef unsigned short u16;
typedef __bf16 bf16x8 __attribute__((ext_vector_type(8)));
typedef float f32x4 __attribute__((ext_vector_type(4)));

typedef const __attribute__((address_space(1))) void gv_t;
typedef __attribute__((address_space(3))) void lv_t;

#define NN 2048
#define DD 1024
#define SS 49
#define CC 1000
#define CP 1024

#define BK 64
#define KK DD
#define NT (KK / BK)   // 16 K-steps

// pool geometry: half-unit = 128 rows x 49 floats = 25088 B
#define HALF_BYTES  25088
#define HALF_CHUNKS 1568           // 16B chunks per half-unit
#define N_HALVES    ((NN * DD) / 128)   // 16384
#define POOL_BLKS   768

__device__ inline u16 f2bf(float f) {
    __hip_bfloat16 h = __float2bfloat16(f);
    union { __hip_bfloat16 h; u16 u; } cv; cv.h = h; return cv.u;
}

// ---- 64x64 MFMA GEMM core: 3-buffer, 2-deep prefetch, counted vmcnt --------
// (r7 core, verified) One raw s_barrier per K-step; vmcnt(4) keeps next
// tile's 4 global_load_lds in flight across the barrier. XOR swizzle via
// pre-swizzled GLOBAL source (linear LDS dest) + same XOR on read.
__device__ __forceinline__ void gemm64_core(const u16* __restrict__ A,
                                            const u16* __restrict__ Bt,
                                            int m0, int n0, char* smem,
                                            f32x4 acc[2][2], int tid) {
    const int lane = tid & 63;
    const int wr = (tid >> 6) >> 1, wc = (tid >> 6) & 1;
    const int r16 = lane & 15, hk = lane >> 4;
    const char* Ab = (const char*)A;
    const char* Bb = (const char*)Bt;

    auto stage = [&](int buf, int k0) {
        #pragma unroll
        for (int j = 0; j < 2; j++) {
            const int c = j * 256 + tid;
            const int row = c >> 3, slot = c & 7;
            const int goff = ((slot ^ (row & 7)) << 4);
            __builtin_amdgcn_global_load_lds(
                (gv_t*)(Ab + ((size_t)(m0 + row) * KK + k0) * 2 + goff),
                (lv_t*)(smem + buf * 16384 + c * 16), 16, 0, 0);
            __builtin_amdgcn_global_load_lds(
                (gv_t*)(Bb + ((size_t)(n0 + row) * KK + k0) * 2 + goff),
                (lv_t*)(smem + buf * 16384 + 8192 + c * 16), 16, 0, 0);
        }
    };

    stage(0, 0);
    stage(1, BK);
    for (int t = 0; t < NT; ++t) {
        if (t + 1 < NT) asm volatile("s_waitcnt vmcnt(4)" ::: "memory");
        else            asm volatile("s_waitcnt vmcnt(0)" ::: "memory");
        __builtin_amdgcn_s_barrier();
        __builtin_amdgcn_sched_barrier(0);
        if (t + 2 < NT) stage((t + 2) % 3, (t + 2) * BK);

        const char* As = smem + (t % 3) * 16384;
        const char* Bs = As + 8192;
        bf16x8 a[2][2], b[2][2];
        #pragma unroll
        for (int mi = 0; mi < 2; mi++) {
            const int row = wr * 32 + mi * 16 + r16;
            #pragma unroll
            for (int kk2 = 0; kk2 < 2; kk2++) {
                const int g = kk2 * 4 + hk;
                a[mi][kk2] = *(const bf16x8*)(As + row * 128 + ((g ^ (row & 7)) << 4));
            }
        }
        #pragma unroll
        for (int ni = 0; ni < 2; ni++) {
            const int row = wc * 32 + ni * 16 + r16;
            #pragma unroll
            for (int kk2 = 0; kk2 < 2; kk2++) {
                const int g = kk2 * 4 + hk;
                b[ni][kk2] = *(const bf16x8*)(Bs + row * 128 + ((g ^ (row & 7)) << 4));
            }
        }
        #pragma unroll
        for (int kk2 = 0; kk2 < 2; kk2++)
            #pragma unroll
            for (int mi = 0; mi < 2; mi++)
                #pragma unroll
                for (int ni = 0; ni < 2; ni++)
                    acc[mi][ni] = __builtin_amdgcn_mfma_f32_16x16x32_bf16(
                        a[mi][kk2], b[ni][kk2], acc[mi][ni], 0, 0, 0);
    }
}

// ---- L0: prep. q = bf16(P+P^T); mu_bf zero-padded; zero qzh/qmuh. ----------
__global__ __launch_bounds__(256) void prep_k(const float* __restrict__ P,
                                              const float* __restrict__ mu,
                                              u16* __restrict__ q,
                                              u16* __restrict__ mu_bf,
                                              float* __restrict__ qzh,
                                              float* __restrict__ qmuh) {
    int i = blockIdx.x * 256 + threadIdx.x;      // 0 .. DD*DD-1
    int r = i >> 10, c = i & 1023;
    q[i]     = f2bf(P[i] + P[c * DD + r]);
    mu_bf[i] = f2bf(r < CC ? mu[i] : 0.f);
    if (i < NN) qzh[i]  = 0.f;
    if (i < CP) qmuh[i] = 0.f;
}

// ---- L1: muQ GEMM (256 blocks, XCD-swizzled) + pipelined pool (768) --------
// muQ decode: xcd = bid&7, local = bid>>3 -> m-blocks {2*xcd, 2*xcd+1} x all
// 16 n. Per-XCD working set: A(mu_bf) 256KB + B(q) 2MB -> L2-resident.
__global__ __launch_bounds__(256) void pool_muq_k(const float* __restrict__ x,
                                                  const u16* __restrict__ q,
                                                  const u16* __restrict__ mu_bf,
                                                  const float* __restrict__ mu,
                                                  u16* __restrict__ b_bf,
                                                  float* __restrict__ qmuh,
                                                  float* __restrict__ zf,
                                                  u16* __restrict__ zb) {
    __shared__ char smem[50176];   // pool: 2 x 25088 dbuf; gemm: 3 x 16K
    const int tid = threadIdx.x;
    const int bid = blockIdx.x;

    if (bid >= 256) {
        // ---------------- pipelined pool (r8, perf == simple pool) ----------
        const int pb = bid - 256;              // 0..767
        char* bufA = smem;
        char* bufB = smem + HALF_BYTES;
        const char* xb = (const char*)x;

        auto issue = [&](char* buf, int H) {
            const char* src = xb + (size_t)H * HALF_BYTES;
            #pragma unroll
            for (int i = 0; i < 7; i++) {
                const int c = i * 256 + tid;
                if (c < HALF_CHUNKS)
                    __builtin_amdgcn_global_load_lds(
                        (gv_t*)(src + c * 16), (lv_t*)(buf + c * 16), 16, 0, 0);
            }
        };

        int H = pb;
        char* cur = bufA;
        char* nxt = bufB;
        issue(cur, H);
        while (H < N_HALVES) {
            asm volatile("s_waitcnt vmcnt(0)" ::: "memory");  // current landed
            __builtin_amdgcn_s_barrier();
            __builtin_amdgcn_sched_barrier(0);
            const int Hn = H + POOL_BLKS;
            if (Hn < N_HALVES) issue(nxt, Hn);                // prefetch next
            if (tid < 128) {                                  // reduce current
                const float* row = (const float*)cur + tid * SS;
                float s = 0.f;
                #pragma unroll
                for (int j = 0; j < SS; j++) s += row[j];
                s *= (1.f / 49.f);
                const size_t o = (size_t)H * 128 + tid;
                zf[o] = s;
                zb[o] = f2bf(s);
            }
            char* t_ = cur; cur = nxt; nxt = t_;
            H = Hn;
        }
        return;
    }

    // ---------------- muQ GEMM tile (b_bf + qmuh), XCD-swizzled -------------
    const int xcd = bid & 7, local = bid >> 3;          // local in [0,32)
    const int m0 = (xcd * 2 + (local >> 4)) * 64;       // m-block in [0,16)
    const int n0 = (local & 15) * 64;
    f32x4 acc[2][2] = {};
    gemm64_core(mu_bf, q, m0, n0, smem, acc, tid);

    const int lane = tid & 63;
    const int wr = (tid >> 6) >> 1, wc = (tid >> 6) & 1;
    const int cr = (lane >> 4) * 4, cc2 = lane & 15;
    #pragma unroll
    for (int mi = 0; mi < 2; mi++) {
        const int gr0 = m0 + wr * 32 + mi * 16 + cr;
        #pragma unroll
        for (int r = 0; r < 4; r++) {
            const int row = gr0 + r;
            float v = 0.f;
            #pragma unroll
            for (int ni = 0; ni < 2; ni++) {
                const int gc = n0 + wc * 32 + ni * 16 + cc2;
                float av = acc[mi][ni][r];
                float sv = (row < CC) ? mu[(size_t)row * DD + gc] : 0.f;
                v += av * sv;
                b_bf[(size_t)row * DD + gc] = f2bf(av);
            }
            #pragma unroll
            for (int m = 1; m < 16; m <<= 1) v += __shfl_xor(v, m);
            if (cc2 == 0) atomicAdd(qmuh + row, 0.25f * v);
        }
    }
}

// ---- L2: zQ-diag + score-partial, XCD-locality swizzled --------------------
// bid -> xcd = bid&7, local = bid>>3 in [0,128). XCDs 0-3: zQ-diag, XCDs
// 4-7: score. Each XCD owns 8 m-blocks x 16 n: per-XCD working set =
// A-panel 1MB + B-panel 2MB = 3MB < 4MB L2 -> each operand byte enters the
// XCD's L2 once (aggregate L3 fetch ~24MB vs 256MB unswizzled).
// score writes out[n,c] = 0.5*acc - qmuh[c]; qzh subtracted by L3 fixup.
__global__ __launch_bounds__(256) void zgemm_k(const u16* __restrict__ z_bf,
                                               const u16* __restrict__ q,
                                               const u16* __restrict__ b_bf,
                                               const float* __restrict__ zf,
                                               float* __restrict__ qzh,
                                               const float* __restrict__ qmuh,
                                               float* __restrict__ out) {
    __shared__ char smem[49152];
    const int tid = threadIdx.x;
    const int bid = blockIdx.x;
    const int xcd = bid & 7, local = bid >> 3;          // local in [0,128)
    const bool isZqd = (xcd < 4);
    const int m0 = ((xcd & 3) * 8 + (local >> 4)) * 64; // m-block in [0,32)
    const int n0 = (local & 15) * 64;
    const int lane = tid & 63;
    const int wr = (tid >> 6) >> 1, wc = (tid >> 6) & 1;
    const int cr = (lane >> 4) * 4, cc2 = lane & 15;

    if (isZqd) {
        // zQ-diag tile: qzh[row] += 0.25 * sum_gc (zQ)[row,gc] * zf[row,gc]
        f32x4 acc[2][2] = {};
        gemm64_core(z_bf, q, m0, n0, smem, acc, tid);
        #pragma unroll
        for (int mi = 0; mi < 2; mi++) {
            const int gr0 = m0 + wr * 32 + mi * 16 + cr;
            #pragma unroll
            for (int r = 0; r < 4; r++) {
                const int row = gr0 + r;
                float v = 0.f;
                #pragma unroll
                for (int ni = 0; ni < 2; ni++) {
                    const int gc = n0 + wc * 32 + ni * 16 + cc2;
                    v += acc[mi][ni][r] * zf[(size_t)row * DD + gc];
                }
                #pragma unroll
                for (int m = 1; m < 16; m <<= 1) v += __shfl_xor(v, m);
                if (cc2 == 0) atomicAdd(qzh + row, 0.25f * v);
            }
        }
    } else {
        // score tile
        f32x4 acc[2][2] = {};
        gemm64_core(z_bf, b_bf, m0, n0, smem, acc, tid);
        #pragma unroll
        for (int mi = 0; mi < 2; mi++) {
            #pragma unroll
            for (int ni = 0; ni < 2; ni++) {
                const int gr = m0 + wr * 32 + mi * 16 + cr;
                const int gc = n0 + wc * 32 + ni * 16 + cc2;
                if (gc < CC) {
                    const float qm = qmuh[gc];
                    #pragma unroll
                    for (int r = 0; r < 4; r++)
                        out[(size_t)(gr + r) * CC + gc] =
                            0.5f * acc[mi][ni][r] - qm;
                }
            }
        }
    }
}

// ---- L3: in-place fixup out[n,c] -= qzh[n] ---------------------------------
__global__ __launch_bounds__(256) void fixup_k(float* __restrict__ out,
                                               const float* __restrict__ qzh) {
    const int n = blockIdx.x, tid = threadIdx.x;
    if (tid >= 250) return;
    const float qz = qzh[n];
    float4* p = (float4*)(out + (size_t)n * CC + tid * 4);
    float4 v = *p;
    v.x -= qz; v.y -= qz; v.z -= qz; v.w -= qz;
    *p = v;
}

extern "C" void kernel_launch(void* const* d_in, const int* in_sizes, int n_in,
                              void* d_out, int out_size, void* d_ws, size_t ws_size,
                              hipStream_t stream) {
    const float* x  = (const float*)d_in[0];   // [N, D, S]
    const float* mu = (const float*)d_in[1];   // [C, D]
    const float* P  = (const float*)d_in[2];   // [D, D]
    float* out = (float*)d_out;                // [N, C]

    // workspace carve (~18.3 MB)
    char* w = (char*)d_ws;
    u16*   q_bf  = (u16*)w;   w += (size_t)DD * DD * 2;   // 2 MB
    u16*   mu_bf = (u16*)w;   w += (size_t)CP * DD * 2;   // 2 MB
    u16*   b_bf  = (u16*)w;   w += (size_t)CP * DD * 2;   // 2 MB
    u16*   z_bf  = (u16*)w;   w += (size_t)NN * DD * 2;   // 4 MB
    float* zf    = (float*)w; w += (size_t)NN * DD * 4;   // 8 MB
    float* qzh   = (float*)w; w += (size_t)NN * 4;
    float* qmuh  = (float*)w;

    // L0: prep (q, mu_bf, zero accumulators)
    prep_k<<<(DD * DD) / 256, 256, 0, stream>>>(P, mu, q_bf, mu_bf, qzh, qmuh);
    // L1: muQ (256, XCD-swizzled) + pipelined persistent pool (768)
    pool_muq_k<<<256 + POOL_BLKS, 256, 0, stream>>>(
        x, q_bf, mu_bf, mu, b_bf, qmuh, zf, z_bf);
    // L2: zQ-diag + score-partial (1024, XCD-locality swizzled) -> out
    zgemm_k<<<1024, 256, 0, stream>>>(z_bf, q_bf, b_bf, zf, qzh, qmuh, out);
    // L3: out[n,:] -= qzh[n] in place
    fixup_k<<<NN, 256, 0, stream>>>(out, qzh);
}

// Round 10
// 119.996 us; speedup vs baseline: 1.0480x; 1.0480x over previous
//
#include <hip/hip_runtime.h>
#include <hip/hip_bf16.h>

typedef unsigned short u16;
typedef __bf16 bf16x8 __attribute__((ext_vector_type(8)));
typedef float f32x4 __attribute__((ext_vector_type(4)));

typedef const __attribute__((address_space(1))) void gv_t;
typedef __attribute__((address_space(3))) void lv_t;

#define NN 2048
#define DD 1024
#define SS 49
#define CC 1000
#define CP 1024

#define BK 64
#define KK DD
#define NT (KK / BK)   // 16 K-steps

__device__ inline u16 f2bf(float f) {
    __hip_bfloat16 h = __float2bfloat16(f);
    union { __hip_bfloat16 h; u16 u; } cv; cv.h = h; return cv.u;
}

// ---- 64x64 MFMA GEMM core: 2-phase double-buffer, 32KB LDS -----------------
// (the r3/r6 core — best measured rounds; 32KB -> 5 blocks/CU so a 1024-block
// grid is fully co-resident, vs 3/CU for the 48KB 3-buffer variant.)
// XOR swizzle via pre-swizzled GLOBAL source (linear LDS dest, rule
// both-sides-or-neither) + same XOR on the read side.
__device__ __forceinline__ void gemm64_core(const u16* __restrict__ A,
                                            const u16* __restrict__ Bt,
                                            int m0, int n0, char* smem,
                                            f32x4 acc[2][2], int tid) {
    char* As = smem;            // [2][8192]
    char* Bs = smem + 16384;    // [2][8192]
    const int lane = tid & 63;
    const int wr = (tid >> 6) >> 1, wc = (tid >> 6) & 1;
    const int r16 = lane & 15, hk = lane >> 4;
    const char* Ab = (const char*)A;
    const char* Bb = (const char*)Bt;

    auto stage = [&](int buf, int k0) {
        #pragma unroll
        for (int j = 0; j < 2; j++) {
            const int c = j * 256 + tid;
            const int row = c >> 3, slot = c & 7;
            const int goff = ((slot ^ (row & 7)) << 4);
            __builtin_amdgcn_global_load_lds(
                (gv_t*)(Ab + ((size_t)(m0 + row) * KK + k0) * 2 + goff),
                (lv_t*)(As + buf * 8192 + c * 16), 16, 0, 0);
            __builtin_amdgcn_global_load_lds(
                (gv_t*)(Bb + ((size_t)(n0 + row) * KK + k0) * 2 + goff),
                (lv_t*)(Bs + buf * 8192 + c * 16), 16, 0, 0);
        }
    };

    stage(0, 0);
    __syncthreads();
    int cur = 0;
    for (int t = 0; t < NT; ++t) {
        if (t + 1 < NT) stage(cur ^ 1, (t + 1) * BK);
        bf16x8 a[2][2], b[2][2];
        #pragma unroll
        for (int mi = 0; mi < 2; mi++) {
            const int row = wr * 32 + mi * 16 + r16;
            #pragma unroll
            for (int kk2 = 0; kk2 < 2; kk2++) {
                const int g = kk2 * 4 + hk;
                a[mi][kk2] = *(const bf16x8*)(As + cur * 8192 + row * 128 + ((g ^ (row & 7)) << 4));
            }
        }
        #pragma unroll
        for (int ni = 0; ni < 2; ni++) {
            const int row = wc * 32 + ni * 16 + r16;
            #pragma unroll
            for (int kk2 = 0; kk2 < 2; kk2++) {
                const int g = kk2 * 4 + hk;
                b[ni][kk2] = *(const bf16x8*)(Bs + cur * 8192 + row * 128 + ((g ^ (row & 7)) << 4));
            }
        }
        #pragma unroll
        for (int kk2 = 0; kk2 < 2; kk2++)
            #pragma unroll
            for (int mi = 0; mi < 2; mi++)
                #pragma unroll
                for (int ni = 0; ni < 2; ni++)
                    acc[mi][ni] = __builtin_amdgcn_mfma_f32_16x16x32_bf16(
                        a[mi][kk2], b[ni][kk2], acc[mi][ni], 0, 0, 0);
        __syncthreads();
        cur ^= 1;
    }
}

// ---- L0: prep via LDS tile transpose ---------------------------------------
// q[r][c] = bf16(P[r][c] + P[c][r]). The old prep read P[c*DD+r] with lanes
// striding 4KB -> 64B line per 4B used = 16x overfetch on 4MB. Fix: block
// (br,bc) loads BOTH 64x64 tiles P[br,bc] and P[bc,br] coalesced into LDS
// (pad 65 to kill transpose-read bank conflicts), adds t1[r][c]+t2[c][r],
// writes q coalesced. Each block also casts a contiguous 4096-elem chunk of
// mu and helps zero qzh/qmuh. 256 blocks total.
__global__ __launch_bounds__(256) void prep_k(const float* __restrict__ P,
                                              const float* __restrict__ mu,
                                              u16* __restrict__ q,
                                              u16* __restrict__ mu_bf,
                                              float* __restrict__ qzh,
                                              float* __restrict__ qmuh) {
    __shared__ float t1[64][65];
    __shared__ float t2[64][65];
    const int tid = threadIdx.x, bid = blockIdx.x;
    const int br = bid >> 4, bc = bid & 15;
    const int br64 = br * 64, bc64 = bc * 64;

    #pragma unroll
    for (int it = 0; it < 16; it++) {
        const int idx = it * 256 + tid;
        const int row = idx >> 6, col = idx & 63;
        t1[row][col] = P[(size_t)(br64 + row) * DD + bc64 + col];
        t2[row][col] = P[(size_t)(bc64 + row) * DD + br64 + col];
    }
    __syncthreads();
    #pragma unroll
    for (int it = 0; it < 16; it++) {
        const int idx = it * 256 + tid;
        const int row = idx >> 6, col = idx & 63;
        q[(size_t)(br64 + row) * DD + bc64 + col] = f2bf(t1[row][col] + t2[col][row]);
    }

    // mu cast (contiguous chunk) + accumulator zeroing
    const size_t base = (size_t)bid * 4096;
    #pragma unroll
    for (int it = 0; it < 16; it++) {
        const size_t j = base + it * 256 + tid;
        const int r = (int)(j >> 10);
        mu_bf[j] = f2bf(r < CC ? mu[j] : 0.f);
    }
    const int g = bid * 256 + tid;
    if (g < NN) qzh[g]  = 0.f;
    if (g < CP) qmuh[g] = 0.f;
}

// ---- L1: muQ GEMM (256 blocks, dispatched first) + pool (8192 blocks) ------
// Pool = r6's verified version: one 256-row unit per block, LDS-staged
// coalesced float4, per-thread row reduce (stride 49 odd -> 2-way alias,
// free). Work distribution by dispatch order (no persistent stragglers).
__global__ __launch_bounds__(256) void pool_muq_k(const float* __restrict__ x,
                                                  const u16* __restrict__ q,
                                                  const u16* __restrict__ mu_bf,
                                                  const float* __restrict__ mu,
                                                  u16* __restrict__ b_bf,
                                                  float* __restrict__ qmuh,
                                                  float* __restrict__ zf,
                                                  u16* __restrict__ zb) {
    __shared__ char smem[50176];   // pool: float[12544]; gemm: 2x16KB dbuf
    const int tid = threadIdx.x;
    const int bid = blockIdx.x;

    if (bid >= 256) {
        // ---------------- pool unit ----------------
        const int u = bid - 256;
        float* lds = (float*)smem;
        const size_t base = (size_t)u * (256 * SS);
        const float4* src = (const float4*)(x + base);
        float4* dst = (float4*)lds;
        #pragma unroll
        for (int i = 0; i < 13; i++) {
            int idx = i * 256 + tid;
            if (idx < (256 * SS) / 4) dst[idx] = src[idx];
        }
        __syncthreads();
        const float* r = lds + tid * SS;
        float s = 0.f;
        #pragma unroll
        for (int j = 0; j < SS; j++) s += r[j];
        s *= (1.f / 49.f);
        size_t o = (size_t)u * 256 + tid;
        zf[o] = s;
        zb[o] = f2bf(s);
        return;
    }

    // ---------------- muQ GEMM tile (b_bf + qmuh) ----------------
    const int m0 = (bid >> 4) * 64, n0 = (bid & 15) * 64;
    f32x4 acc[2][2] = {};
    gemm64_core(mu_bf, q, m0, n0, smem, acc, tid);

    const int lane = tid & 63;
    const int wr = (tid >> 6) >> 1, wc = (tid >> 6) & 1;
    const int cr = (lane >> 4) * 4, cc2 = lane & 15;
    #pragma unroll
    for (int mi = 0; mi < 2; mi++) {
        const int gr0 = m0 + wr * 32 + mi * 16 + cr;
        #pragma unroll
        for (int r = 0; r < 4; r++) {
            const int row = gr0 + r;
            float v = 0.f;
            #pragma unroll
            for (int ni = 0; ni < 2; ni++) {
                const int gc = n0 + wc * 32 + ni * 16 + cc2;
                float av = acc[mi][ni][r];
                float sv = (row < CC) ? mu[(size_t)row * DD + gc] : 0.f;
                v += av * sv;
                b_bf[(size_t)row * DD + gc] = f2bf(av);
            }
            #pragma unroll
            for (int m = 1; m < 16; m <<= 1) v += __shfl_xor(v, m);
            if (cc2 == 0) atomicAdd(qmuh + row, 0.25f * v);
        }
    }
}

// ---- L2: zQ-diag (bid<512) + score-partial (512) ---------------------------
// 32KB core -> 5 blocks/CU -> all 1024 blocks co-resident (single wave).
// score writes out[n,c] = 0.5*acc - qmuh[c]; qzh subtracted by L3 fixup, so
// the two roles are fully independent.
__global__ __launch_bounds__(256) void zgemm_k(const u16* __restrict__ z_bf,
                                               const u16* __restrict__ q,
                                               const u16* __restrict__ b_bf,
                                               const float* __restrict__ zf,
                                               float* __restrict__ qzh,
                                               const float* __restrict__ qmuh,
                                               float* __restrict__ out) {
    __shared__ char smem[32768];
    const int tid = threadIdx.x;
    const int bid = blockIdx.x;
    const int lane = tid & 63;
    const int wr = (tid >> 6) >> 1, wc = (tid >> 6) & 1;
    const int cr = (lane >> 4) * 4, cc2 = lane & 15;

    if (bid < 512) {
        // zQ-diag tile: qzh[row] += 0.25 * sum_gc (zQ)[row,gc] * zf[row,gc]
        const int m0 = (bid >> 4) * 64, n0 = (bid & 15) * 64;
        f32x4 acc[2][2] = {};
        gemm64_core(z_bf, q, m0, n0, smem, acc, tid);
        #pragma unroll
        for (int mi = 0; mi < 2; mi++) {
            const int gr0 = m0 + wr * 32 + mi * 16 + cr;
            #pragma unroll
            for (int r = 0; r < 4; r++) {
                const int row = gr0 + r;
                float v = 0.f;
                #pragma unroll
                for (int ni = 0; ni < 2; ni++) {
                    const int gc = n0 + wc * 32 + ni * 16 + cc2;
                    v += acc[mi][ni][r] * zf[(size_t)row * DD + gc];
                }
                #pragma unroll
                for (int m = 1; m < 16; m <<= 1) v += __shfl_xor(v, m);
                if (cc2 == 0) atomicAdd(qzh + row, 0.25f * v);
            }
        }
    } else {
        // score tile
        const int i = bid - 512;
        const int m0 = (i >> 4) * 64, n0 = (i & 15) * 64;
        f32x4 acc[2][2] = {};
        gemm64_core(z_bf, b_bf, m0, n0, smem, acc, tid);
        #pragma unroll
        for (int mi = 0; mi < 2; mi++) {
            #pragma unroll
            for (int ni = 0; ni < 2; ni++) {
                const int gr = m0 + wr * 32 + mi * 16 + cr;
                const int gc = n0 + wc * 32 + ni * 16 + cc2;
                if (gc < CC) {
                    const float qm = qmuh[gc];
                    #pragma unroll
                    for (int r = 0; r < 4; r++)
                        out[(size_t)(gr + r) * CC + gc] =
                            0.5f * acc[mi][ni][r] - qm;
                }
            }
        }
    }
}

// ---- L3: in-place fixup out[n,c] -= qzh[n] ---------------------------------
__global__ __launch_bounds__(256) void fixup_k(float* __restrict__ out,
                                               const float* __restrict__ qzh) {
    const int n = blockIdx.x, tid = threadIdx.x;
    if (tid >= 250) return;
    const float qz = qzh[n];
    float4* p = (float4*)(out + (size_t)n * CC + tid * 4);
    float4 v = *p;
    v.x -= qz; v.y -= qz; v.z -= qz; v.w -= qz;
    *p = v;
}

extern "C" void kernel_launch(void* const* d_in, const int* in_sizes, int n_in,
                              void* d_out, int out_size, void* d_ws, size_t ws_size,
                              hipStream_t stream) {
    const float* x  = (const float*)d_in[0];   // [N, D, S]
    const float* mu = (const float*)d_in[1];   // [C, D]
    const float* P  = (const float*)d_in[2];   // [D, D]
    float* out = (float*)d_out;                // [N, C]

    // workspace carve (~18.3 MB)
    char* w = (char*)d_ws;
    u16*   q_bf  = (u16*)w;   w += (size_t)DD * DD * 2;   // 2 MB
    u16*   mu_bf = (u16*)w;   w += (size_t)CP * DD * 2;   // 2 MB
    u16*   b_bf  = (u16*)w;   w += (size_t)CP * DD * 2;   // 2 MB
    u16*   z_bf  = (u16*)w;   w += (size_t)NN * DD * 2;   // 4 MB
    float* zf    = (float*)w; w += (size_t)NN * DD * 4;   // 8 MB
    float* qzh   = (float*)w; w += (size_t)NN * 4;
    float* qmuh  = (float*)w;

    // L0: prep via LDS tile transpose (coalesced P^T) + mu cast + zeroing
    prep_k<<<256, 256, 0, stream>>>(P, mu, q_bf, mu_bf, qzh, qmuh);
    // L1: muQ (256, first) + pool (8192, one unit per block)
    pool_muq_k<<<256 + (NN * DD) / 256, 256, 0, stream>>>(
        x, q_bf, mu_bf, mu, b_bf, qmuh, zf, z_bf);
    // L2: zQ-diag (512) + score-partial (512) -> out (minus qmuh only)
    zgemm_k<<<1024, 256, 0, stream>>>(z_bf, q_bf, b_bf, zf, qzh, qmuh, out);
    // L3: out[n,:] -= qzh[n] in place
    fixup_k<<<NN, 256, 0, stream>>>(out, qzh);
}